// Round 9
// baseline (343.349 us; speedup 1.0000x reference)
//
#include <hip/hip_runtime.h>

#define TT 140
#define BB 8192
#define HH 64
#define BT 16   // batch tile per wave (MFMA N)
#define HS 68   // h stride in bf16 elems (136 B): b64 frags conflict-free (R7: ~0 conflicts)

typedef __bf16 bf16x8 __attribute__((ext_vector_type(8)));
typedef __bf16 bf16x4 __attribute__((ext_vector_type(4)));
typedef float  f32x4  __attribute__((ext_vector_type(4)));
typedef float  f32x2  __attribute__((ext_vector_type(2)));

#define MFMA(a,b,c) __builtin_amdgcn_mfma_f32_16x16x32_bf16(a, b, c, 0, 0, 0)

__device__ __forceinline__ float fast_tanh(float a) {
    float e = __builtin_amdgcn_exp2f(a * 2.88539008178f);
    return 1.0f - 2.0f * __builtin_amdgcn_rcpf(e + 1.0f);
}

// Load one B-fragment (8 bf16) from an 8-B-aligned LDS address as 2x b64.
__device__ __forceinline__ bf16x8 load_bfrag(const __bf16* p) {
    bf16x4 a = *(const bf16x4*)(p);
    bf16x4 b = *(const bf16x4*)(p + 4);
    return __builtin_shufflevector(a, b, 0, 1, 2, 3, 4, 5, 6, 7);
}

__device__ __forceinline__ void cvt_frag(const float* p, bf16x8& hi, bf16x8& lo) {
    f32x4 wa = *(const f32x4*)p;
    f32x4 wb = *(const f32x4*)(p + 4);
    #pragma unroll
    for (int j = 0; j < 8; ++j) {
        float f = (j < 4) ? wa[j] : wb[j - 4];
        __bf16 h = (__bf16)f;
        hi[j] = h;
        lo[j] = (__bf16)(f - (float)h);
    }
}

// Opaque pin: value becomes asm output -> remat-from-global is illegal,
// and at launch_bounds(64,1) (512 VGPR budget) there is no pressure to spill.
__device__ __forceinline__ void pin(bf16x8& v) {
    f32x4 t = __builtin_bit_cast(f32x4, v);
    asm volatile("" : "+v"(t));
    v = __builtin_bit_cast(bf16x8, t);
}
__device__ __forceinline__ void pinf(float& v) { asm volatile("" : "+v"(v)); }

// 1 wave = 16 batches, both layers, all 64 units. State in wave-private LDS.
// One barrier (lgkm drain) per step: h0n write -> cross-lane read RAW fence.
// h1 parity-double-buffered so its RAW is covered by the same barrier.
__global__ __launch_bounds__(64, 1)
void rnn_kernel(const float* __restrict__ x,
                const float* __restrict__ h_state,
                const float* __restrict__ W_ih0,
                const float* __restrict__ W_hh0,
                const float* __restrict__ b_ih0,
                const float* __restrict__ b_hh0,
                const float* __restrict__ W_ih1,
                const float* __restrict__ W_hh1,
                const float* __restrict__ b_ih1,
                const float* __restrict__ b_hh1,
                const float* __restrict__ W_out,
                const float* __restrict__ b_out,
                float* __restrict__ out)
{
    __shared__ __align__(16) __bf16 h0hi[BT * HS], h0lo[BT * HS];
    __shared__ __align__(16) __bf16 h1hi[2][BT * HS], h1lo[2][BT * HS];
    __shared__ float xs[TT * 17];     // x staged [t][b]
    __shared__ float outs[TT * 17];   // y staged [t][b]

    const int lane = threadIdx.x;     // block = one wave
    const int col  = lane & 15;       // MFMA col (batch)
    const int q    = lane >> 4;       // quad
    const int b0   = blockIdx.x * BT;

    // ---- A-fragments: all weights resident across 140 steps (192 VGPRs) ----
    bf16x8 A0h[4][2], A0l[4][2];      // W_hh0
    bf16x8 A1h[4][4], A1l[4][4];      // kt0-1 = W_ih1, kt2-3 = W_hh1
    #pragma unroll
    for (int mt = 0; mt < 4; ++mt) {
        #pragma unroll
        for (int kt = 0; kt < 2; ++kt) {
            const int off = (16 * mt + col) * HH + 32 * kt + 8 * q;
            cvt_frag(W_hh0 + off, A0h[mt][kt], A0l[mt][kt]);
            cvt_frag(W_ih1 + off, A1h[mt][kt], A1l[mt][kt]);
            cvt_frag(W_hh1 + off, A1h[mt][kt + 2], A1l[mt][kt + 2]);
        }
    }
    #pragma unroll
    for (int mt = 0; mt < 4; ++mt) {
        #pragma unroll
        for (int kt = 0; kt < 2; ++kt) { pin(A0h[mt][kt]); pin(A0l[mt][kt]); }
        #pragma unroll
        for (int kt = 0; kt < 4; ++kt) { pin(A1h[mt][kt]); pin(A1l[mt][kt]); }
    }

    // ---- epilogue scalars, j = 16mt + 4q + r (64 VGPRs, pinned) ----
    float bias0v[16], bias1v[16], wih0v[16], woutv[16];
    #pragma unroll
    for (int mt = 0; mt < 4; ++mt) {
        #pragma unroll
        for (int r = 0; r < 4; ++r) {
            int j = 16 * mt + 4 * q + r;
            bias0v[4 * mt + r] = b_ih0[j] + b_hh0[j];
            bias1v[4 * mt + r] = b_ih1[j] + b_hh1[j];
            wih0v[4 * mt + r]  = W_ih0[j];
            woutv[4 * mt + r]  = W_out[j];
        }
    }
    #pragma unroll
    for (int i = 0; i < 16; ++i) {
        pinf(bias0v[i]); pinf(bias1v[i]); pinf(wih0v[i]); pinf(woutv[i]);
    }
    const float bout = b_out[0];

    // ---- stage x[b0..b0+15][0..139] into LDS [t][b] ----
    for (int b = 0; b < BT; ++b) {
        #pragma unroll
        for (int c = 0; c < 3; ++c) {
            int t = c * 64 + lane;
            if (t < TT) xs[t * 17 + b] = x[(size_t)(b0 + b) * TT + t];
        }
    }
    // ---- init hidden state ([2,B,H]); h1 initial parity = 1 (t=-1) ----
    #pragma unroll
    for (int b = 0; b < BT; ++b) {
        float v0 = h_state[(size_t)(b0 + b) * HH + lane];
        float v1 = h_state[(size_t)BB * HH + (size_t)(b0 + b) * HH + lane];
        __bf16 c0 = (__bf16)v0;
        h0hi[b * HS + lane] = c0;
        h0lo[b * HS + lane] = (__bf16)(v0 - (float)c0);
        __bf16 c1 = (__bf16)v1;
        h1hi[1][b * HS + lane] = c1;
        h1lo[1][b * HS + lane] = (__bf16)(v1 - (float)c1);
    }
    __syncthreads();

    #pragma unroll 1
    for (int t = 0; t < TT; ++t) {
        const int wb = t & 1, rb = 1 - wb;   // h1 parity buffers

        // ---- layer 0: read h0(t-1) frags (program-order before writes: WAR-safe)
        bf16x8 bh[2], bl[2];
        #pragma unroll
        for (int kt = 0; kt < 2; ++kt) {
            bh[kt] = load_bfrag(&h0hi[col * HS + 32 * kt + 8 * q]);
            bl[kt] = load_bfrag(&h0lo[col * HS + 32 * kt + 8 * q]);
        }
        float xt = xs[t * 17 + col];
        #pragma unroll
        for (int mt = 0; mt < 4; ++mt) {
            f32x4 c0 = {0,0,0,0}, c1 = {0,0,0,0}, c2 = {0,0,0,0};
            #pragma unroll
            for (int kt = 0; kt < 2; ++kt) {
                c0 = MFMA(A0h[mt][kt], bh[kt], c0);   // hi*hi
                c1 = MFMA(A0h[mt][kt], bl[kt], c1);   // hi*lo
                c2 = MFMA(A0l[mt][kt], bh[kt], c2);   // lo*hi
            }
            f32x4 a = c0 + (c1 + c2);
            bf16x4 hi4, lo4;
            #pragma unroll
            for (int r = 0; r < 4; ++r) {
                float pre = a[r] + bias0v[4 * mt + r] + wih0v[4 * mt + r] * xt;
                float hn  = fast_tanh(pre);
                __bf16 h  = (__bf16)hn;
                hi4[r] = h;
                lo4[r] = (__bf16)(hn - (float)h);
            }
            *(bf16x4*)(&h0hi[col * HS + 16 * mt + 4 * q]) = hi4;
            *(bf16x4*)(&h0lo[col * HS + 16 * mt + 4 * q]) = lo4;
        }
        __syncthreads();  // ONLY fence per step: h0n + h1(t-1) RAW drain

        // ---- layer 1: h0n (kt0-1) + h1(t-1)@rb (kt2-3) ----
        bf16x8 ch[4], cl[4];
        #pragma unroll
        for (int kt = 0; kt < 2; ++kt) {
            ch[kt]     = load_bfrag(&h0hi[col * HS + 32 * kt + 8 * q]);
            cl[kt]     = load_bfrag(&h0lo[col * HS + 32 * kt + 8 * q]);
            ch[kt + 2] = load_bfrag(&h1hi[rb][col * HS + 32 * kt + 8 * q]);
            cl[kt + 2] = load_bfrag(&h1lo[rb][col * HS + 32 * kt + 8 * q]);
        }
        float p = 0.f;
        #pragma unroll
        for (int mt = 0; mt < 4; ++mt) {
            f32x4 c0 = {0,0,0,0}, c1 = {0,0,0,0}, c2 = {0,0,0,0};
            #pragma unroll
            for (int kt = 0; kt < 4; ++kt) {
                c0 = MFMA(A1h[mt][kt], ch[kt], c0);
                c1 = MFMA(A1h[mt][kt], cl[kt], c1);
                c2 = MFMA(A1l[mt][kt], ch[kt], c2);
            }
            f32x4 a = c0 + (c1 + c2);
            bf16x4 hi4, lo4;
            #pragma unroll
            for (int r = 0; r < 4; ++r) {
                float pre = a[r] + bias1v[4 * mt + r];
                float hn  = fast_tanh(pre);
                p += hn * woutv[4 * mt + r];
                __bf16 h = (__bf16)hn;
                hi4[r] = h;
                lo4[r] = (__bf16)(hn - (float)h);
            }
            *(bf16x4*)(&h1hi[wb][col * HS + 16 * mt + 4 * q]) = hi4;
            *(bf16x4*)(&h1lo[wb][col * HS + 16 * mt + 4 * q]) = lo4;
        }
        p += __shfl_xor(p, 16, 64);
        p += __shfl_xor(p, 32, 64);
        if (lane < 16) outs[t * 17 + lane] = p + bout;
        // no end-of-step barrier: next L0 reads h0 (fenced last step), next L1's
        // h1 read is fenced by next step's mid barrier; WAR safe by program order
    }
    __syncthreads();  // outs + final h visible across lanes

    // ---- epilogue: staged y -> global ----
    for (int b = 0; b < BT; ++b) {
        #pragma unroll
        for (int c = 0; c < 3; ++c) {
            int t = c * 64 + lane;
            if (t < TT) out[(size_t)(b0 + b) * TT + t] = outs[t * 17 + b];
        }
    }
    // ---- h_final: [2,B,H] after out[B*T]; h1 final parity = 139&1 = 1 ----
    const size_t OFF = (size_t)BB * TT;
    #pragma unroll
    for (int b = 0; b < BT; ++b) {
        float v0 = (float)h0hi[b * HS + lane] + (float)h0lo[b * HS + lane];
        float v1 = (float)h1hi[1][b * HS + lane] + (float)h1lo[1][b * HS + lane];
        out[OFF + (size_t)(b0 + b) * HH + lane] = v0;
        out[OFF + (size_t)BB * HH + (size_t)(b0 + b) * HH + lane] = v1;
    }
}

extern "C" void kernel_launch(void* const* d_in, const int* in_sizes, int n_in,
                              void* d_out, int out_size, void* d_ws, size_t ws_size,
                              hipStream_t stream) {
    const float* x      = (const float*)d_in[0];
    const float* hst    = (const float*)d_in[1];
    const float* W_ih0  = (const float*)d_in[2];
    const float* W_hh0  = (const float*)d_in[3];
    const float* b_ih0  = (const float*)d_in[4];
    const float* b_hh0  = (const float*)d_in[5];
    const float* W_ih1  = (const float*)d_in[6];
    const float* W_hh1  = (const float*)d_in[7];
    const float* b_ih1  = (const float*)d_in[8];
    const float* b_hh1  = (const float*)d_in[9];
    const float* W_out  = (const float*)d_in[10];
    const float* b_outp = (const float*)d_in[11];
    float* out = (float*)d_out;

    dim3 grid(BB / BT);   // 512 one-wave blocks (2 waves/CU)
    dim3 block(64);
    rnn_kernel<<<grid, block, 0, stream>>>(x, hst, W_ih0, W_hh0, b_ih0, b_hh0,
                                           W_ih1, W_hh1, b_ih1, b_hh1,
                                           W_out, b_outp, out);
}

// Round 10
// 286.606 us; speedup vs baseline: 1.1980x; 1.1980x over previous
//
#include <hip/hip_runtime.h>

#define TT 140
#define BB 8192
#define HH 64
#define BT 16   // batch tile per block (MFMA N)
#define HS 68   // h stride in bf16 elems (136 B): b64 frag pattern conflict-free (R9: 0 conflicts)

typedef __bf16 bf16x8 __attribute__((ext_vector_type(8)));
typedef __bf16 bf16x4 __attribute__((ext_vector_type(4)));
typedef float  f32x4  __attribute__((ext_vector_type(4)));

#define MFMA(a,b,c) __builtin_amdgcn_mfma_f32_16x16x32_bf16(a, b, c, 0, 0, 0)

__device__ __forceinline__ float fast_tanh(float a) {
    float e = __builtin_amdgcn_exp2f(a * 2.88539008178f);
    return 1.0f - 2.0f * __builtin_amdgcn_rcpf(e + 1.0f);
}

// One B-fragment (8 bf16) from an 8-B-aligned LDS address (2x b64 / ds_read2_b64).
__device__ __forceinline__ bf16x8 load_bfrag(const __bf16* p) {
    bf16x4 a = *(const bf16x4*)(p);
    bf16x4 b = *(const bf16x4*)(p + 4);
    return __builtin_shufflevector(a, b, 0, 1, 2, 3, 4, 5, 6, 7);
}

__device__ __forceinline__ void cvt_frag(const float* p, bf16x8& hi, bf16x8& lo) {
    f32x4 wa = *(const f32x4*)p;
    f32x4 wb = *(const f32x4*)(p + 4);
    #pragma unroll
    for (int j = 0; j < 8; ++j) {
        float f = (j < 4) ? wa[j] : wb[j - 4];
        __bf16 h = (__bf16)f;
        hi[j] = h;
        lo[j] = (__bf16)(f - (float)h);
    }
}

// Block = 2 waves, one 16-batch tile. Wave w owns units 32w..32w+31, BOTH layers.
// Static per-wave weight set = 96+32 VGPRs (allocator-friendly; cf. R6 VGPR=72 resident,
// R9's 256-value set spilled). One barrier/step; h0,h1,pp parity-double-buffered.
__global__ __launch_bounds__(128, 1)
void rnn_kernel(const float* __restrict__ x,
                const float* __restrict__ h_state,
                const float* __restrict__ W_ih0,
                const float* __restrict__ W_hh0,
                const float* __restrict__ b_ih0,
                const float* __restrict__ b_hh0,
                const float* __restrict__ W_ih1,
                const float* __restrict__ W_hh1,
                const float* __restrict__ b_ih1,
                const float* __restrict__ b_hh1,
                const float* __restrict__ W_out,
                const float* __restrict__ b_out,
                float* __restrict__ out)
{
    __shared__ __align__(16) __bf16 h0hi[2][BT * HS], h0lo[2][BT * HS];
    __shared__ __align__(16) __bf16 h1hi[2][BT * HS], h1lo[2][BT * HS];
    __shared__ float xs[TT * 17];     // x staged [t][b]
    __shared__ float outs[TT * 17];   // y staged [t][b]
    __shared__ float pp[2][2][20];    // projection partials [parity][wave][batch]

    const int tid  = threadIdx.x;
    const int w    = tid >> 6;        // 0..1: unit half
    const int lane = tid & 63;
    const int col  = lane & 15;       // MFMA col (batch)
    const int q    = lane >> 4;       // quad
    const int b0   = blockIdx.x * BT;

    // ---- A-fragments for this wave's 32 units (mt = 2w+mm); resident all steps ----
    bf16x8 A0h[2][2], A0l[2][2];      // W_hh0 [mm][kt]
    bf16x8 A1h[2][4], A1l[2][4];      // [mm][kt]: kt0-1 = W_ih1, kt2-3 = W_hh1
    #pragma unroll
    for (int mm = 0; mm < 2; ++mm) {
        #pragma unroll
        for (int kt = 0; kt < 2; ++kt) {
            const int off = (16 * (2 * w + mm) + col) * HH + 32 * kt + 8 * q;
            cvt_frag(W_hh0 + off, A0h[mm][kt], A0l[mm][kt]);
            cvt_frag(W_ih1 + off, A1h[mm][kt], A1l[mm][kt]);
            cvt_frag(W_hh1 + off, A1h[mm][kt + 2], A1l[mm][kt + 2]);
        }
    }
    // ---- epilogue scalars, j = 16*(2w+mm) + 4q + r ----
    float bias0v[8], bias1v[8], wih0v[8], woutv[8];
    #pragma unroll
    for (int mm = 0; mm < 2; ++mm) {
        #pragma unroll
        for (int r = 0; r < 4; ++r) {
            int j = 16 * (2 * w + mm) + 4 * q + r;
            bias0v[4 * mm + r] = b_ih0[j] + b_hh0[j];
            bias1v[4 * mm + r] = b_ih1[j] + b_hh1[j];
            wih0v[4 * mm + r]  = W_ih0[j];
            woutv[4 * mm + r]  = W_out[j];
        }
    }
    const float bout = b_out[0];

    // ---- stage x[b0..b0+15][0..139] into LDS [t][b] ----
    for (int c = 0; c < (TT * BT + 127) / 128; ++c) {
        int i = c * 128 + tid;
        if (i < TT * BT) {
            int t = i >> 4, b = i & 15;
            xs[t * 17 + b] = x[(size_t)(b0 + b) * TT + t];
        }
    }
    // ---- init hidden state into parity-1 buffers (step "-1") ----
    #pragma unroll
    for (int c = 0; c < (BT * HH) / 128; ++c) {
        int i = c * 128 + tid;
        int b = i >> 6, u = i & 63;
        float v0 = h_state[(size_t)(b0 + b) * HH + u];
        float v1 = h_state[(size_t)BB * HH + (size_t)(b0 + b) * HH + u];
        __bf16 c0 = (__bf16)v0;
        h0hi[1][b * HS + u] = c0;
        h0lo[1][b * HS + u] = (__bf16)(v0 - (float)c0);
        __bf16 c1 = (__bf16)v1;
        h1hi[1][b * HS + u] = c1;
        h1lo[1][b * HS + u] = (__bf16)(v1 - (float)c1);
    }
    __syncthreads();

    const int fb    = col * HS + 8 * q;                 // frag base (+32*kt)
    const int wbase = col * HS + 32 * w + 4 * q;        // write base (+16*mm)

    auto do_step = [&](int t, int PAR) {
        // ---- L0: read h0(t-1)@(1-PAR), write h0(t)@PAR ----
        bf16x8 bh[2], bl[2];
        #pragma unroll
        for (int kt = 0; kt < 2; ++kt) {
            bh[kt] = load_bfrag(&h0hi[1 - PAR][fb + 32 * kt]);
            bl[kt] = load_bfrag(&h0lo[1 - PAR][fb + 32 * kt]);
        }
        float xt = xs[t * 17 + col];
        #pragma unroll
        for (int mm = 0; mm < 2; ++mm) {
            f32x4 c0 = {0,0,0,0}, c1 = {0,0,0,0}, c2 = {0,0,0,0};
            #pragma unroll
            for (int kt = 0; kt < 2; ++kt) {
                c0 = MFMA(A0h[mm][kt], bh[kt], c0);   // hi*hi
                c1 = MFMA(A0h[mm][kt], bl[kt], c1);   // hi*lo
                c2 = MFMA(A0l[mm][kt], bh[kt], c2);   // lo*hi
            }
            f32x4 a = c0 + (c1 + c2);
            bf16x4 hi4, lo4;
            #pragma unroll
            for (int r = 0; r < 4; ++r) {
                float pre = a[r] + bias0v[4 * mm + r] + wih0v[4 * mm + r] * xt;
                float hn  = fast_tanh(pre);
                __bf16 h  = (__bf16)hn;
                hi4[r] = h;
                lo4[r] = (__bf16)(hn - (float)h);
            }
            *(bf16x4*)(&h0hi[PAR][wbase + 16 * mm]) = hi4;
            *(bf16x4*)(&h0lo[PAR][wbase + 16 * mm]) = lo4;
        }
        __syncthreads();   // the ONE barrier: h0n visible; h1(t-1), pp(t-1) stable

        // folder: outs(t-1) from pp(t-1)@(1-PAR) (written before the barrier above)
        if (w == 0 && t >= 1 && lane < 16)
            outs[(t - 1) * 17 + lane] = pp[1 - PAR][0][lane] + pp[1 - PAR][1][lane] + bout;

        // ---- L1: read h0n@PAR + h1(t-1)@(1-PAR); write h1(t)@PAR ----
        bf16x8 ch[4], cl[4];
        #pragma unroll
        for (int kt = 0; kt < 2; ++kt) {
            ch[kt]     = load_bfrag(&h0hi[PAR][fb + 32 * kt]);
            cl[kt]     = load_bfrag(&h0lo[PAR][fb + 32 * kt]);
            ch[kt + 2] = load_bfrag(&h1hi[1 - PAR][fb + 32 * kt]);
            cl[kt + 2] = load_bfrag(&h1lo[1 - PAR][fb + 32 * kt]);
        }
        float p = 0.f;
        #pragma unroll
        for (int mm = 0; mm < 2; ++mm) {
            f32x4 c0 = {0,0,0,0}, c1 = {0,0,0,0}, c2 = {0,0,0,0};
            #pragma unroll
            for (int kt = 0; kt < 4; ++kt) {
                c0 = MFMA(A1h[mm][kt], ch[kt], c0);
                c1 = MFMA(A1h[mm][kt], cl[kt], c1);
                c2 = MFMA(A1l[mm][kt], ch[kt], c2);
            }
            f32x4 a = c0 + (c1 + c2);
            bf16x4 hi4, lo4;
            #pragma unroll
            for (int r = 0; r < 4; ++r) {
                float pre = a[r] + bias1v[4 * mm + r];
                float hn  = fast_tanh(pre);
                p += hn * woutv[4 * mm + r];
                __bf16 h = (__bf16)hn;
                hi4[r] = h;
                lo4[r] = (__bf16)(hn - (float)h);
            }
            *(bf16x4*)(&h1hi[PAR][wbase + 16 * mm]) = hi4;
            *(bf16x4*)(&h1lo[PAR][wbase + 16 * mm]) = lo4;
        }
        p += __shfl_xor(p, 16, 64);
        p += __shfl_xor(p, 32, 64);
        if (lane < 16) pp[PAR][w][lane] = p;
        // no trailing barrier: next step's L0 touches only h0 (fenced above);
        // h1/pp parities it writes were last read before the barrier we passed.
    };

    #pragma unroll 1
    for (int pb = 0; pb < TT; pb += 2) {
        do_step(pb, 0);
        do_step(pb + 1, 1);
    }
    __syncthreads();
    if (w == 0 && lane < 16)   // tail fold: step 139 partials (parity 1)
        outs[(TT - 1) * 17 + lane] = pp[1][0][lane] + pp[1][1][lane] + bout;
    __syncthreads();

    // ---- epilogue: staged y -> global; wave w covers batches 8w..8w+7 ----
    for (int bi = 0; bi < 8; ++bi) {
        int b = 8 * w + bi;
        #pragma unroll
        for (int c = 0; c < 3; ++c) {
            int t = c * 64 + lane;
            if (t < TT) out[(size_t)(b0 + b) * TT + t] = outs[t * 17 + b];
        }
    }
    // ---- h_final: [2,B,H] after out[B*T]; final parity = 139&1 = 1 ----
    const size_t OFF = (size_t)BB * TT;
    #pragma unroll
    for (int c = 0; c < (BT * HH) / 128; ++c) {
        int i = c * 128 + tid;
        int b = i >> 6, u = i & 63;
        float v0 = (float)h0hi[1][b * HS + u] + (float)h0lo[1][b * HS + u];
        float v1 = (float)h1hi[1][b * HS + u] + (float)h1lo[1][b * HS + u];
        out[OFF + (size_t)(b0 + b) * HH + u] = v0;
        out[OFF + (size_t)BB * HH + (size_t)(b0 + b) * HH + u] = v1;
    }
}

extern "C" void kernel_launch(void* const* d_in, const int* in_sizes, int n_in,
                              void* d_out, int out_size, void* d_ws, size_t ws_size,
                              hipStream_t stream) {
    const float* x      = (const float*)d_in[0];
    const float* hst    = (const float*)d_in[1];
    const float* W_ih0  = (const float*)d_in[2];
    const float* W_hh0  = (const float*)d_in[3];
    const float* b_ih0  = (const float*)d_in[4];
    const float* b_hh0  = (const float*)d_in[5];
    const float* W_ih1  = (const float*)d_in[6];
    const float* W_hh1  = (const float*)d_in[7];
    const float* b_ih1  = (const float*)d_in[8];
    const float* b_hh1  = (const float*)d_in[9];
    const float* W_out  = (const float*)d_in[10];
    const float* b_outp = (const float*)d_in[11];
    float* out = (float*)d_out;

    dim3 grid(BB / BT);   // 512 blocks x 2 waves = 1024 waves (4/CU, 1/SIMD)
    dim3 block(128);
    rnn_kernel<<<grid, block, 0, stream>>>(x, hst, W_ih0, W_hh0, b_ih0, b_hh0,
                                           W_ih1, W_hh1, b_ih1, b_hh1,
                                           W_out, b_outp, out);
}